// Round 12
// baseline (34.492 us; speedup 1.0000x reference)
//
#include <hip/hip_runtime.h>
#include <math.h>

#define ISZ   64
#define NPIX  4096
#define BNB   4
#define NFACE 1024
#define NT8   64            // 8x8 grid of 8x8-px tiles
#define CHB   128           // faces staged per LDS chunk (single chunk for most tiles)
#define NEARP 1.0f
#define FARP  100.0f
#define EPSV  0.001f
#define INV_SIGMA 1.0e5f
#define INV_GAMMA 1.0e4f
#define THRESH 9.210240366975849e-5f  // SIGMA*log(1/DIST_EPS - 1)
#define RDIL  0.0105f                 // > sqrt(THRESH)=0.009597, fp margin
#define NQ    12                      // 11 const quads + 1 bbox int4

typedef float vf4 __attribute__((ext_vector_type(4)));  // native vec for NT stores

__device__ __forceinline__ float frcp(float x){ return __builtin_amdgcn_rcpf(x); }
__device__ __forceinline__ float clamp01(float x){ return fminf(fmaxf(x, 0.0f), 1.0f); }

__device__ __forceinline__ void nt_store4(float* p, float a, float b, float c, float d){
    vf4 v; v.x = a; v.y = b; v.z = c; v.w = d;
    __builtin_nontemporal_store(v, (vf4*)p);
}

__device__ __forceinline__ float edge_d2q(float px, float py, float4 E, float4 F){
    float tt = clamp01(E.x*px + E.y*py + E.z);
    float dx = px - F.x - tt*F.z;
    float dy = py - F.y - tt*F.w;
    return dx*dx + dy*dy;
}

struct Ev { float znm, D, coef, s, wc0, wc1, wc2; };
__device__ __forceinline__ Ev face_pixel(const float4* __restrict__ cf,
                                         float px, float py)
{
    Ev r;
    float4 A = cf[0], Bq = cf[1], E0 = cf[2], F0 = cf[3];
    float4 E1 = cf[4], F1 = cf[5], E2 = cf[6], F2 = cf[7];
    float w0 = A.x*px + A.y*py + A.z;
    float w1 = Bq.x*px + Bq.y*py + Bq.z;
    float w2 = 1.0f - w0 - w1;
    bool inside = (w0 > 0.0f) && (w1 > 0.0f) && (w2 > 0.0f);
    float d2 = fminf(fminf(edge_d2q(px,py,E0,F0), edge_d2q(px,py,E1,F1)),
                     edge_d2q(px,py,E2,F2));
    float wc0 = clamp01(w0), wc1 = clamp01(w1), wc2 = clamp01(w2);
    float s = wc0 + wc1 + wc2 + 1e-12f;
    float tz = wc0*A.w + wc1*Bq.w + wc2*E0.w;
    float zp = s * frcp(tz);
    bool valid = (zp > NEARP) && (zp < FARP);
    float zn = (FARP - zp) * (1.0f/(FARP - NEARP));
    bool covered = valid && (inside || (d2 < THRESH));
    r.znm = covered ? zn : -1.0f;
    float x = d2 * INV_SIGMA;
    float e = __expf(inside ? -x : x);
    float D = frcp(1.0f + e);
    if (!inside && d2 >= THRESH) D = 0.0f;
    r.D = D;
    r.coef = valid ? D : 0.0f;
    r.s = s; r.wc0 = wc0; r.wc1 = wc1; r.wc2 = wc2;
    return r;
}

// Dilated integer bbox (row_lo,row_hi,quadcol_lo,quadcol_hi). Identical float
// ops everywhere -> identical result -> fill/writer sets are exact complements.
__device__ __forceinline__ int4 face_bbox(const float* __restrict__ v){
    float x0=v[0], y0=v[1], x1=v[3], y1=v[4], x2=v[6], y2=v[7];
    float xmn = fminf(fminf(x0,x1),x2) - RDIL, xmx = fmaxf(fmaxf(x0,x1),x2) + RDIL;
    float ymn = fminf(fminf(y0,y1),y2) - RDIL, ymx = fmaxf(fmaxf(y0,y1),y2) + RDIL;
    int jl = (int)ceilf (32.0f*xmn + 31.5f);
    int jh = (int)floorf(32.0f*xmx + 31.5f);
    int il = (int)ceilf (31.5f - 32.0f*ymx);
    int ih = (int)floorf(31.5f - 32.0f*ymn);
    jl = max(jl, 0); jh = min(jh, 63); il = max(il, 0); ih = min(ih, 63);
    int4 bb; bb.x = il; bb.y = ih; bb.z = jl >> 2; bb.w = jh >> 2;
    return bb;
}

__device__ __forceinline__ void face_consts(const float* __restrict__ v,
                                            const float* __restrict__ t,
                                            float4* __restrict__ o){
    float x0=v[0],y0=v[1],z0=v[2],x1=v[3],y1=v[4],z1=v[5],x2=v[6],y2=v[7],z2=v[8];
    float a0 = y1 - y2, a1 = x2 - x1;
    float det = a0*(x0 - x2) + a1*(y0 - y2);
    det = (fabsf(det) < 1e-10f) ? 1e-10f : det;
    float rdet = 1.0f/det;
    float b0 = y2 - y0, b1 = x0 - x2;
    o[0] = make_float4(a0*rdet, a1*rdet, -(a0*x2 + a1*y2)*rdet, 1.0f/z0);
    o[1] = make_float4(b0*rdet, b1*rdet, -(b0*x2 + b1*y2)*rdet, 1.0f/z1);
    float rz2 = 1.0f/z2;
    const float axs[3] = {x0, x1, x2}, ays[3] = {y0, y1, y2};
    const float bxs[3] = {x1, x2, x0}, bys[3] = {y1, y2, y0};
    #pragma unroll
    for (int e = 0; e < 3; ++e) {
        float ex = bxs[e] - axs[e], ey = bys[e] - ays[e];
        float inv = 1.0f/(ex*ex + ey*ey + 1e-12f);
        o[2 + 2*e] = make_float4(ex*inv, ey*inv, -(axs[e]*ex + ays[e]*ey)*inv,
                                 (e == 0) ? rz2 : 0.0f);
        o[3 + 2*e] = make_float4(axs[e], ays[e], ex, ey);
    }
    o[8]  = make_float4(t[0], t[3], t[6], 0.0f);
    o[9]  = make_float4(t[1], t[4], t[7], 0.0f);
    o[10] = make_float4(t[2], t[5], t[8], 0.0f);
    int4 bb = face_bbox(v);
    ((int4*)(o + 11))[0] = bb;
}

// kAll: SINGLE launch.
// Blocks [0,256): tile role — inline bin (bbox->LDS, ballot compact), inline
// constants, online softmax -> images, m/invd in LDS, then final D/aggr for
// every bbox∩tile quad. Blocks [256, 256+4096): fill role — one face per
// block, zero all non-bbox quads of BOTH arrays (nontemporal).
// Exact complements; every output byte written exactly once.
__global__ __launch_bounds__(256) void kAll(const float* __restrict__ fv,
                                            const float* __restrict__ ft,
                                            float* __restrict__ imgs,
                                            float* __restrict__ outD,
                                            float* __restrict__ outW)
{
    const int bid = blockIdx.x, tid = threadIdx.x;

    if (bid >= BNB*NT8) {
        // ---- fill role: one face per block, both output arrays ----
        const int fg = bid - BNB*NT8;
        const size_t fbase = (size_t)fg*NPIX;
        const int4 bb = face_bbox(fv + (size_t)fg*9);
        const int q = tid & 15;
        const int i0 = tid >> 4;
        #pragma unroll
        for (int l = 0; l < 4; ++l) {
            const int i = i0 + 16*l;
            const bool hole = (i >= bb.x) && (i <= bb.y) && (q >= bb.z) && (q <= bb.w);
            if (!hole) {
                const size_t off = fbase + i*64 + q*4;
                nt_store4(outD + off, 0.f, 0.f, 0.f, 0.f);
                nt_store4(outW + off, 0.f, 0.f, 0.f, 0.f);
            }
        }
        return;
    }

    // ---- tile role ----
    __shared__ float4 sfc[CHB*NQ];                  // 24 KiB
    __shared__ unsigned short slist[NFACE];         // 2 KiB
    __shared__ unsigned char  hits[NFACE];          // 1 KiB
    __shared__ int   slen;
    __shared__ float lm[256], lsum[256], lr0[256], lr1[256], lr2[256], lpr[256];
    __shared__ float mF[64], ivF[64];               // final per-pixel m, invd

    const int t = bid & (NT8-1), b = bid >> 6;
    const int ty0 = (t>>3)*8, ty1 = ty0+7;
    const int tx0 = (t&7)*8,  tx1 = tx0+7;

    // step 1: all 256 threads compute 4 bboxes each -> hit flags
    #pragma unroll
    for (int rr = 0; rr < 4; ++rr) {
        const int f = rr*256 + tid;
        int4 bb = face_bbox(fv + (size_t)(b*NFACE + f)*9);
        bool hit = (bb.x <= bb.y) && (bb.z <= bb.w) &&
                   (bb.y >= ty0) && (bb.x <= ty1) &&
                   (bb.w*4 + 3 >= tx0) && (bb.z*4 <= tx1);
        hits[f] = hit ? 1 : 0;
    }
    __syncthreads();

    // step 2: wave 0 ballot-compacts the ordered face list (LDS-only reads)
    if (tid < 64) {
        int base = 0;
        for (int r = 0; r < NFACE/64; ++r) {
            const int f = r*64 + tid;
            bool hit = hits[f] != 0;
            unsigned long long mb = __ballot(hit);
            if (hit) {
                int pos = __popcll(mb & ((1ull << tid) - 1ull));
                slist[base + pos] = (unsigned short)f;
            }
            base += __popcll(mb);
        }
        if (tid == 0) slen = base;
    }
    __syncthreads();
    const int len = slen;

    const int p  = tid & 63;           // pixel within tile
    const int qs = tid >> 6;           // list slice 0..3
    const int i  = ty0 + (p>>3);
    const int j  = tx0 + (p&7);
    const int jq = j >> 2;
    const float px = (2.0f*(float)j + 1.0f - (float)ISZ) * (1.0f/(float)ISZ);
    const float py = ((float)ISZ - 1.0f - 2.0f*(float)i) * (1.0f/(float)ISZ);

    float pm = EPSV, ps = 0.f, p0 = 0.f, p1 = 0.f, p2 = 0.f, ppr = 1.f;

    // ---- pass 1: online softmax over chunks (consts computed inline) ----
    for (int base = 0; base < len; base += CHB) {
        const int n = min(CHB, len - base);
        __syncthreads();
        if (tid < n) {
            const size_t f = (size_t)b*NFACE + slist[base + tid];
            face_consts(fv + f*9, ft + f*9, &sfc[tid*NQ]);
        }
        __syncthreads();
        for (int k = qs; k < n; k += 4) {
            const float4* cf = &sfc[k*NQ];
            int4 bb = ((const int4*)cf)[11];
            bool act = (i >= bb.x) && (i <= bb.y) && (jq >= bb.z) && (jq <= bb.w);
            if (act) {
                Ev r = face_pixel(cf, px, py);
                float wt;
                if (r.znm > pm) {
                    float sc = __expf((pm - r.znm) * INV_GAMMA);
                    ps *= sc; p0 *= sc; p1 *= sc; p2 *= sc;
                    pm = r.znm;
                    wt = r.coef;
                } else {
                    wt = r.coef * __expf((r.znm - pm) * INV_GAMMA);
                }
                float wrs = wt * frcp(r.s);
                float4 X0 = cf[8], X1 = cf[9], X2 = cf[10];
                ps += wt;
                p0 += wrs * (r.wc0*X0.x + r.wc1*X0.y + r.wc2*X0.z);
                p1 += wrs * (r.wc0*X1.x + r.wc1*X1.y + r.wc2*X1.z);
                p2 += wrs * (r.wc0*X2.x + r.wc1*X2.y + r.wc2*X2.z);
                ppr *= (1.0f - r.D);
            }
        }
    }

    lm[tid] = pm; lsum[tid] = ps; lr0[tid] = p0; lr1[tid] = p1; lr2[tid] = p2;
    lpr[tid] = ppr;
    __syncthreads();

    // ---- merge + images; keep m/invd in LDS ----
    if (tid < 64) {
        float m = EPSV;
        #pragma unroll
        for (int s = 0; s < 4; ++s) m = fmaxf(m, lm[s*64 + tid]);
        float denom = __expf((EPSV - m) * INV_GAMMA);   // wbg
        float r0 = 0.f, r1 = 0.f, r2 = 0.f, pr = 1.f;
        #pragma unroll
        for (int s = 0; s < 4; ++s) {
            const int o = s*64 + tid;
            float e = __expf((lm[o] - m) * INV_GAMMA);
            denom += lsum[o] * e;
            r0 += lr0[o] * e;
            r1 += lr1[o] * e;
            r2 += lr2[o] * e;
            pr *= lpr[o];
        }
        float invd = frcp(denom);
        mF[tid] = m; ivF[tid] = invd;
        const int ii = ty0 + (tid>>3);
        const int jj = tx0 + (tid&7);
        const int pix = ii*64 + jj;
        size_t ip = (size_t)b*4*NPIX + pix;
        imgs[ip]          = r0 * invd;   // BG = 0
        imgs[ip +   NPIX] = r1 * invd;
        imgs[ip + 2*NPIX] = r2 * invd;
        imgs[ip + 3*NPIX] = 1.0f - pr;
    }
    __syncthreads();

    // ---- pass 2: final D/aggr writes for bbox∩tile quads (16 thr/face) ----
    const int k0 = tid >> 4, sub = tid & 15;
    const int rloc = sub >> 1, cloc = sub & 1;     // row in tile, qcol in tile
    const int wi = ty0 + rloc;                     // global row
    const int wq = (tx0 >> 2) + cloc;              // global quadcol
    const float wpy = ((float)ISZ - 1.0f - 2.0f*(float)wi) * (1.0f/(float)ISZ);

    for (int base = 0; base < len; base += CHB) {
        const int n = min(CHB, len - base);
        if (len > CHB) {                           // restage only when chunked
            __syncthreads();
            if (tid < n) {
                const size_t f = (size_t)b*NFACE + slist[base + tid];
                face_consts(fv + f*9, ft + f*9, &sfc[tid*NQ]);
            }
            __syncthreads();
        }
        for (int k = k0; k < n; k += 16) {
            const float4* cf = &sfc[k*NQ];
            const int4 bb = ((const int4*)cf)[11];
            if (wi < bb.x || wi > bb.y || wq < bb.z || wq > bb.w) continue;
            float D[4], W[4];
            #pragma unroll
            for (int l = 0; l < 4; ++l) {
                const int jj = wq*4 + l;
                const float wpx = (2.0f*(float)jj + 1.0f - (float)ISZ) * (1.0f/(float)ISZ);
                Ev r = face_pixel(cf, wpx, wpy);
                const int lp = rloc*8 + (jj - tx0);     // local pixel 0..63
                D[l] = r.D;
                W[l] = r.coef * __expf((r.znm - mF[lp]) * INV_GAMMA) * ivF[lp];
            }
            const size_t off = ((size_t)b*NFACE + slist[base + k])*NPIX + wi*64 + wq*4;
            nt_store4(outD + off, D[0], D[1], D[2], D[3]);
            nt_store4(outW + off, W[0], W[1], W[2], W[3]);
        }
    }
}

extern "C" void kernel_launch(void* const* d_in, const int* in_sizes, int n_in,
                              void* d_out, int out_size, void* d_ws, size_t ws_size,
                              hipStream_t stream) {
    const float* fv = (const float*)d_in[0];
    const float* ft = (const float*)d_in[1];
    float* out  = (float*)d_out;
    float* imgs = out;
    float* outD = out + (size_t)BNB*4*NPIX;
    float* outA = outD + (size_t)BNB*NFACE*NPIX;

    const int nFill = BNB*NFACE;               // 4096
    kAll<<<BNB*NT8 + nFill, 256, 0, stream>>>(fv, ft, imgs, outD, outA);
}

// Round 13
// 23.761 us; speedup vs baseline: 1.4516x; 1.4516x over previous
//
#include <hip/hip_runtime.h>
#include <math.h>

#define ISZ   64
#define NPIX  4096
#define BNB   4
#define NFACE 1024
#define NT8   64            // 8x8 grid of 8x8-px tiles
#define CHB   128           // faces staged per LDS chunk (single chunk for most tiles)
#define NEARP 1.0f
#define FARP  100.0f
#define EPSV  0.001f
#define INV_SIGMA 1.0e5f
#define INV_GAMMA 1.0e4f
#define THRESH 9.210240366975849e-5f  // SIGMA*log(1/DIST_EPS - 1)
#define RDIL  0.0105f                 // > sqrt(THRESH)=0.009597, fp margin
#define NQ    12                      // 11 const quads + 1 bbox int4

__device__ __forceinline__ float frcp(float x){ return __builtin_amdgcn_rcpf(x); }
__device__ __forceinline__ float clamp01(float x){ return fminf(fmaxf(x, 0.0f), 1.0f); }

__device__ __forceinline__ float edge_d2q(float px, float py, float4 E, float4 F){
    float tt = clamp01(E.x*px + E.y*py + E.z);
    float dx = px - F.x - tt*F.z;
    float dy = py - F.y - tt*F.w;
    return dx*dx + dy*dy;
}

struct Ev { float znm, D, coef, s, wc0, wc1, wc2; };
__device__ __forceinline__ Ev face_pixel(const float4* __restrict__ cf,
                                         float px, float py)
{
    Ev r;
    float4 A = cf[0], Bq = cf[1], E0 = cf[2], F0 = cf[3];
    float4 E1 = cf[4], F1 = cf[5], E2 = cf[6], F2 = cf[7];
    float w0 = A.x*px + A.y*py + A.z;
    float w1 = Bq.x*px + Bq.y*py + Bq.z;
    float w2 = 1.0f - w0 - w1;
    bool inside = (w0 > 0.0f) && (w1 > 0.0f) && (w2 > 0.0f);
    float d2 = fminf(fminf(edge_d2q(px,py,E0,F0), edge_d2q(px,py,E1,F1)),
                     edge_d2q(px,py,E2,F2));
    float wc0 = clamp01(w0), wc1 = clamp01(w1), wc2 = clamp01(w2);
    float s = wc0 + wc1 + wc2 + 1e-12f;
    float tz = wc0*A.w + wc1*Bq.w + wc2*E0.w;
    float zp = s * frcp(tz);
    bool valid = (zp > NEARP) && (zp < FARP);
    float zn = (FARP - zp) * (1.0f/(FARP - NEARP));
    bool covered = valid && (inside || (d2 < THRESH));
    r.znm = covered ? zn : -1.0f;
    float x = d2 * INV_SIGMA;
    float e = __expf(inside ? -x : x);
    float D = frcp(1.0f + e);
    if (!inside && d2 >= THRESH) D = 0.0f;
    r.D = D;
    r.coef = valid ? D : 0.0f;
    r.s = s; r.wc0 = wc0; r.wc1 = wc1; r.wc2 = wc2;
    return r;
}

// Dilated integer bbox (row_lo,row_hi,quadcol_lo,quadcol_hi). Identical float
// ops everywhere -> identical result -> fill/writer sets are exact complements.
__device__ __forceinline__ int4 face_bbox(const float* __restrict__ v){
    float x0=v[0], y0=v[1], x1=v[3], y1=v[4], x2=v[6], y2=v[7];
    float xmn = fminf(fminf(x0,x1),x2) - RDIL, xmx = fmaxf(fmaxf(x0,x1),x2) + RDIL;
    float ymn = fminf(fminf(y0,y1),y2) - RDIL, ymx = fmaxf(fmaxf(y0,y1),y2) + RDIL;
    int jl = (int)ceilf (32.0f*xmn + 31.5f);
    int jh = (int)floorf(32.0f*xmx + 31.5f);
    int il = (int)ceilf (31.5f - 32.0f*ymx);
    int ih = (int)floorf(31.5f - 32.0f*ymn);
    jl = max(jl, 0); jh = min(jh, 63); il = max(il, 0); ih = min(ih, 63);
    int4 bb; bb.x = il; bb.y = ih; bb.z = jl >> 2; bb.w = jh >> 2;
    return bb;
}

__device__ __forceinline__ void face_consts(const float* __restrict__ v,
                                            const float* __restrict__ t,
                                            float4* __restrict__ o){
    float x0=v[0],y0=v[1],z0=v[2],x1=v[3],y1=v[4],z1=v[5],x2=v[6],y2=v[7],z2=v[8];
    float a0 = y1 - y2, a1 = x2 - x1;
    float det = a0*(x0 - x2) + a1*(y0 - y2);
    det = (fabsf(det) < 1e-10f) ? 1e-10f : det;
    float rdet = 1.0f/det;
    float b0 = y2 - y0, b1 = x0 - x2;
    o[0] = make_float4(a0*rdet, a1*rdet, -(a0*x2 + a1*y2)*rdet, 1.0f/z0);
    o[1] = make_float4(b0*rdet, b1*rdet, -(b0*x2 + b1*y2)*rdet, 1.0f/z1);
    float rz2 = 1.0f/z2;
    const float axs[3] = {x0, x1, x2}, ays[3] = {y0, y1, y2};
    const float bxs[3] = {x1, x2, x0}, bys[3] = {y1, y2, y0};
    #pragma unroll
    for (int e = 0; e < 3; ++e) {
        float ex = bxs[e] - axs[e], ey = bys[e] - ays[e];
        float inv = 1.0f/(ex*ex + ey*ey + 1e-12f);
        o[2 + 2*e] = make_float4(ex*inv, ey*inv, -(axs[e]*ex + ays[e]*ey)*inv,
                                 (e == 0) ? rz2 : 0.0f);
        o[3 + 2*e] = make_float4(axs[e], ays[e], ex, ey);
    }
    o[8]  = make_float4(t[0], t[3], t[6], 0.0f);
    o[9]  = make_float4(t[1], t[4], t[7], 0.0f);
    o[10] = make_float4(t[2], t[5], t[8], 0.0f);
    int4 bb = face_bbox(v);
    ((int4*)(o + 11))[0] = bb;
}

// kAll: SINGLE launch.
// Blocks [0,256): tile role — inline bin (bbox->LDS, ballot compact), inline
// constants, online softmax -> images, m/invd in LDS, then final D/aggr for
// every bbox∩tile quad. Blocks [256, 256+4096): fill role — one face per
// block, zero all non-bbox quads of BOTH arrays (plain float4 stores; NT
// stores regressed 10 µs in R12 — they bypass L2 write-combining).
// Exact complements; every output byte written exactly once.
__global__ __launch_bounds__(256) void kAll(const float* __restrict__ fv,
                                            const float* __restrict__ ft,
                                            float* __restrict__ imgs,
                                            float* __restrict__ outD,
                                            float* __restrict__ outW)
{
    const int bid = blockIdx.x, tid = threadIdx.x;

    if (bid >= BNB*NT8) {
        // ---- fill role: one face per block, both output arrays ----
        const int fg = bid - BNB*NT8;
        const size_t fbase = (size_t)fg*NPIX;
        const int4 bb = face_bbox(fv + (size_t)fg*9);
        const int q = tid & 15;
        const int i0 = tid >> 4;
        const float4 z = make_float4(0.f,0.f,0.f,0.f);
        #pragma unroll
        for (int l = 0; l < 4; ++l) {
            const int i = i0 + 16*l;
            const bool hole = (i >= bb.x) && (i <= bb.y) && (q >= bb.z) && (q <= bb.w);
            if (!hole) {
                const size_t off = fbase + i*64 + q*4;
                *(float4*)(outD + off) = z;
                *(float4*)(outW + off) = z;
            }
        }
        return;
    }

    // ---- tile role ----
    __shared__ float4 sfc[CHB*NQ];                  // 24 KiB
    __shared__ unsigned short slist[NFACE];         // 2 KiB
    __shared__ unsigned char  hits[NFACE];          // 1 KiB
    __shared__ int   slen;
    __shared__ float lm[256], lsum[256], lr0[256], lr1[256], lr2[256], lpr[256];
    __shared__ float mF[64], ivF[64];               // final per-pixel m, invd

    const int t = bid & (NT8-1), b = bid >> 6;
    const int ty0 = (t>>3)*8, ty1 = ty0+7;
    const int tx0 = (t&7)*8,  tx1 = tx0+7;

    // step 1: all 256 threads compute 4 bboxes each -> hit flags
    #pragma unroll
    for (int rr = 0; rr < 4; ++rr) {
        const int f = rr*256 + tid;
        int4 bb = face_bbox(fv + (size_t)(b*NFACE + f)*9);
        bool hit = (bb.x <= bb.y) && (bb.z <= bb.w) &&
                   (bb.y >= ty0) && (bb.x <= ty1) &&
                   (bb.w*4 + 3 >= tx0) && (bb.z*4 <= tx1);
        hits[f] = hit ? 1 : 0;
    }
    __syncthreads();

    // step 2: wave 0 ballot-compacts the ordered face list (LDS-only reads)
    if (tid < 64) {
        int base = 0;
        for (int r = 0; r < NFACE/64; ++r) {
            const int f = r*64 + tid;
            bool hit = hits[f] != 0;
            unsigned long long mb = __ballot(hit);
            if (hit) {
                int pos = __popcll(mb & ((1ull << tid) - 1ull));
                slist[base + pos] = (unsigned short)f;
            }
            base += __popcll(mb);
        }
        if (tid == 0) slen = base;
    }
    __syncthreads();
    const int len = slen;

    const int p  = tid & 63;           // pixel within tile
    const int qs = tid >> 6;           // list slice 0..3
    const int i  = ty0 + (p>>3);
    const int j  = tx0 + (p&7);
    const int jq = j >> 2;
    const float px = (2.0f*(float)j + 1.0f - (float)ISZ) * (1.0f/(float)ISZ);
    const float py = ((float)ISZ - 1.0f - 2.0f*(float)i) * (1.0f/(float)ISZ);

    float pm = EPSV, ps = 0.f, p0 = 0.f, p1 = 0.f, p2 = 0.f, ppr = 1.f;

    // ---- pass 1: online softmax over chunks (consts computed inline) ----
    for (int base = 0; base < len; base += CHB) {
        const int n = min(CHB, len - base);
        __syncthreads();
        if (tid < n) {
            const size_t f = (size_t)b*NFACE + slist[base + tid];
            face_consts(fv + f*9, ft + f*9, &sfc[tid*NQ]);
        }
        __syncthreads();
        for (int k = qs; k < n; k += 4) {
            const float4* cf = &sfc[k*NQ];
            int4 bb = ((const int4*)cf)[11];
            bool act = (i >= bb.x) && (i <= bb.y) && (jq >= bb.z) && (jq <= bb.w);
            if (act) {
                Ev r = face_pixel(cf, px, py);
                float wt;
                if (r.znm > pm) {
                    float sc = __expf((pm - r.znm) * INV_GAMMA);
                    ps *= sc; p0 *= sc; p1 *= sc; p2 *= sc;
                    pm = r.znm;
                    wt = r.coef;
                } else {
                    wt = r.coef * __expf((r.znm - pm) * INV_GAMMA);
                }
                float wrs = wt * frcp(r.s);
                float4 X0 = cf[8], X1 = cf[9], X2 = cf[10];
                ps += wt;
                p0 += wrs * (r.wc0*X0.x + r.wc1*X0.y + r.wc2*X0.z);
                p1 += wrs * (r.wc0*X1.x + r.wc1*X1.y + r.wc2*X1.z);
                p2 += wrs * (r.wc0*X2.x + r.wc1*X2.y + r.wc2*X2.z);
                ppr *= (1.0f - r.D);
            }
        }
    }

    lm[tid] = pm; lsum[tid] = ps; lr0[tid] = p0; lr1[tid] = p1; lr2[tid] = p2;
    lpr[tid] = ppr;
    __syncthreads();

    // ---- merge + images; keep m/invd in LDS ----
    if (tid < 64) {
        float m = EPSV;
        #pragma unroll
        for (int s = 0; s < 4; ++s) m = fmaxf(m, lm[s*64 + tid]);
        float denom = __expf((EPSV - m) * INV_GAMMA);   // wbg
        float r0 = 0.f, r1 = 0.f, r2 = 0.f, pr = 1.f;
        #pragma unroll
        for (int s = 0; s < 4; ++s) {
            const int o = s*64 + tid;
            float e = __expf((lm[o] - m) * INV_GAMMA);
            denom += lsum[o] * e;
            r0 += lr0[o] * e;
            r1 += lr1[o] * e;
            r2 += lr2[o] * e;
            pr *= lpr[o];
        }
        float invd = frcp(denom);
        mF[tid] = m; ivF[tid] = invd;
        const int ii = ty0 + (tid>>3);
        const int jj = tx0 + (tid&7);
        const int pix = ii*64 + jj;
        size_t ip = (size_t)b*4*NPIX + pix;
        imgs[ip]          = r0 * invd;   // BG = 0
        imgs[ip +   NPIX] = r1 * invd;
        imgs[ip + 2*NPIX] = r2 * invd;
        imgs[ip + 3*NPIX] = 1.0f - pr;
    }
    __syncthreads();

    // ---- pass 2: final D/aggr writes for bbox∩tile quads (16 thr/face) ----
    const int k0 = tid >> 4, sub = tid & 15;
    const int rloc = sub >> 1, cloc = sub & 1;     // row in tile, qcol in tile
    const int wi = ty0 + rloc;                     // global row
    const int wq = (tx0 >> 2) + cloc;              // global quadcol
    const float wpy = ((float)ISZ - 1.0f - 2.0f*(float)wi) * (1.0f/(float)ISZ);

    for (int base = 0; base < len; base += CHB) {
        const int n = min(CHB, len - base);
        if (len > CHB) {                           // restage only when chunked
            __syncthreads();
            if (tid < n) {
                const size_t f = (size_t)b*NFACE + slist[base + tid];
                face_consts(fv + f*9, ft + f*9, &sfc[tid*NQ]);
            }
            __syncthreads();
        }
        for (int k = k0; k < n; k += 16) {
            const float4* cf = &sfc[k*NQ];
            const int4 bb = ((const int4*)cf)[11];
            if (wi < bb.x || wi > bb.y || wq < bb.z || wq > bb.w) continue;
            float D[4], W[4];
            #pragma unroll
            for (int l = 0; l < 4; ++l) {
                const int jj = wq*4 + l;
                const float wpx = (2.0f*(float)jj + 1.0f - (float)ISZ) * (1.0f/(float)ISZ);
                Ev r = face_pixel(cf, wpx, wpy);
                const int lp = rloc*8 + (jj - tx0);     // local pixel 0..63
                D[l] = r.D;
                W[l] = r.coef * __expf((r.znm - mF[lp]) * INV_GAMMA) * ivF[lp];
            }
            const size_t off = ((size_t)b*NFACE + slist[base + k])*NPIX + wi*64 + wq*4;
            *(float4*)(outD + off) = make_float4(D[0],D[1],D[2],D[3]);
            *(float4*)(outW + off) = make_float4(W[0],W[1],W[2],W[3]);
        }
    }
}

extern "C" void kernel_launch(void* const* d_in, const int* in_sizes, int n_in,
                              void* d_out, int out_size, void* d_ws, size_t ws_size,
                              hipStream_t stream) {
    const float* fv = (const float*)d_in[0];
    const float* ft = (const float*)d_in[1];
    float* out  = (float*)d_out;
    float* imgs = out;
    float* outD = out + (size_t)BNB*4*NPIX;
    float* outA = outD + (size_t)BNB*NFACE*NPIX;

    const int nFill = BNB*NFACE;               // 4096
    kAll<<<BNB*NT8 + nFill, 256, 0, stream>>>(fv, ft, imgs, outD, outA);
}